// Round 7
// baseline (411.472 us; speedup 1.0000x reference)
//
#include <hip/hip_runtime.h>

// VQ-VAE quantizer forward. Scores via 1-term bf16 MFMA (zh*wh).
// M=32 rows/block, grid 1024 -> 4 blocks/CU (4 waves/SIMD) for latency hiding.
// B fragments global->reg, depth-2 ring (R4-proven schedule), A from LDS.
// mse recovered from the score accumulator (z read exactly once).
// z: [32, 256, 32, 32] fp32; weight: [256, 1024] fp32.
// out: quantized [8388608] ++ loss [32768] ++ commitment [32768] ++ embedding [32768]

typedef unsigned short ushort_t;
typedef short          s16x8  __attribute__((ext_vector_type(8)));
typedef float          f32x16 __attribute__((ext_vector_type(16)));

__device__ __forceinline__ ushort_t f2bf(float x) {
    unsigned int u = __float_as_uint(x);
    u += 0x7fffu + ((u >> 16) & 1u);          // RNE
    return (ushort_t)(u >> 16);
}
__device__ __forceinline__ float bf2f(ushort_t h) {
    return __uint_as_float(((unsigned int)h) << 16);
}

// ---- prep: transpose + bf16-split W into k-major slabs + wsq, one kernel ----
// slab layout: off(d,k) = (d>>5)*32768 + k*32 + (d&31)   [8 slabs of 1024k x 32d]
__global__ __launch_bounds__(256)
void vq_wprep(const float* __restrict__ w,
              ushort_t* __restrict__ hi, ushort_t* __restrict__ lo,
              float* __restrict__ wsq) {
    __shared__ float tile[64][65];
    __shared__ float psum[64][4];
    const int t  = threadIdx.x;
    const int kt = blockIdx.x;          // 16 blocks, 64 codes each
    const int kk = t >> 2;              // k-local 0..63
    const int dq = t & 3;               // d-quarter within 32-d slab
    float acc = 0.f;
    for (int dt6 = 0; dt6 < 4; ++dt6) {
        __syncthreads();
        #pragma unroll
        for (int i = 0; i < 16; ++i) {
            const int lin = t + 256 * i;
            const int dd = lin >> 6, k2 = lin & 63;
            tile[dd][k2] = w[(size_t)(dt6 * 64 + dd) * 1024 + kt * 64 + k2];
        }
        __syncthreads();
        #pragma unroll
        for (int half = 0; half < 2; ++half) {
            s16x8 hv, lv;
            #pragma unroll
            for (int e = 0; e < 8; ++e) {
                const int dd = half * 32 + dq * 8 + e;
                const float v = tile[dd][kk];
                const ushort_t hb = f2bf(v);
                hv[e] = (short)hb;
                lv[e] = (short)f2bf(v - bf2f(hb));
                acc = fmaf(v, v, acc);
            }
            const size_t base = (size_t)(dt6 * 2 + half) * 32768
                              + (size_t)(kt * 64 + kk) * 32 + dq * 8;
            *reinterpret_cast<s16x8*>(&hi[base]) = hv;
            *reinterpret_cast<s16x8*>(&lo[base]) = lv;
        }
    }
    psum[kk][dq] = acc;
    __syncthreads();
    if (t < 64)
        wsq[kt * 64 + t] = psum[t][0] + psum[t][1] + psum[t][2] + psum[t][3];
}

// ---- main: M=32 rows per block, 1024 blocks ----
__global__ __launch_bounds__(256, 4)
void vq_mfma(const float* __restrict__ z,
             const ushort_t* __restrict__ wh_slab, const ushort_t* __restrict__ wl_slab,
             const float* __restrict__ wsq, float* __restrict__ out) {
    __shared__ ushort_t z_hi[32][268];      // [n][d] pad 268 -> 2-way banks on b128 reads
    __shared__ float    psum[32][32];       // z^2 partials [dr][s]
    __shared__ float    wred_v[4][32];
    __shared__ int      wred_i[4][32];
    __shared__ int      kbest[32];

    const int tid  = threadIdx.x;
    const int bid  = blockIdx.x;
    const int b    = bid >> 5;          // 32 blocks per 1024-elem HW plane
    const int s0   = (bid & 31) * 32;
    const int lane = tid & 63;
    const int wk   = tid >> 6;          // wave id -> k-quarter of each 256-chunk
    const int l31  = lane & 31;
    const int lhi  = lane >> 5;

    // ---- stage z -> z_hi [32 n][256 d] + z^2 partials (z read ONCE) ----
    {
        const int u  = tid & 7;
        const int sc = u * 4;
        const int dr = tid >> 3;        // 0..31
        float p[4] = {0.f, 0.f, 0.f, 0.f};
        #pragma unroll
        for (int it = 0; it < 8; ++it) {
            const int d = it * 32 + dr;
            const float4 v = *reinterpret_cast<const float4*>(
                &z[(((size_t)(b * 256 + d)) << 10) + s0 + sc]);
            const float vv[4] = {v.x, v.y, v.z, v.w};
            #pragma unroll
            for (int jj = 0; jj < 4; ++jj) {
                const int j = (jj + u) & 3;           // stagger write banks
                z_hi[sc + j][d] = f2bf(vv[j]);
                p[j] = fmaf(vv[j], vv[j], p[j]);
            }
        }
        #pragma unroll
        for (int j = 0; j < 4; ++j) psum[dr][sc + j] = p[j];
    }
    __syncthreads();

    const size_t lane_off = (size_t)(wk * 64 + l31) * 32 + lhi * 8;

    float bestv[16];
    int   besti[16];
    #pragma unroll
    for (int r = 0; r < 16; ++r) { bestv[r] = 1e30f; besti[r] = 0; }

    f32x16 acc[2];
    s16x8  bb[2][2];
    for (int c = 0; c < 4; ++c) {           // k-chunks of 256 (rolled)
        #pragma unroll
        for (int nt = 0; nt < 2; ++nt)
            #pragma unroll
            for (int e = 0; e < 16; ++e) acc[nt][e] = 0.f;

        // depth-2 preamble: steps j=0,1 of this chunk
        #pragma unroll
        for (int p = 0; p < 2; ++p) {
            const size_t off = (size_t)(p >> 1) * 32768 + (size_t)((p & 1) * 16)
                             + (size_t)c * 8192 + lane_off;
            bb[p][0] = *reinterpret_cast<const s16x8*>(&wh_slab[off]);
            bb[p][1] = *reinterpret_cast<const s16x8*>(&wh_slab[off + 1024]);
        }

        #pragma unroll
        for (int j = 0; j < 16; ++j) {
            const int slot = j & 1;                     // compile-time
            const s16x8 a0 = *reinterpret_cast<const s16x8*>(
                &z_hi[l31][j * 16 + lhi * 8]);
            acc[0] = __builtin_amdgcn_mfma_f32_32x32x16_bf16(a0, bb[slot][0], acc[0], 0, 0, 0);
            acc[1] = __builtin_amdgcn_mfma_f32_32x32x16_bf16(a0, bb[slot][1], acc[1], 0, 0, 0);
            // prefetch step j+2 into the slot just consumed (WAR keeps order)
            if (j + 2 < 16) {
                const int j2 = j + 2;
                const size_t off = (size_t)(j2 >> 1) * 32768 + (size_t)((j2 & 1) * 16)
                                 + (size_t)c * 8192 + lane_off;
                bb[slot][0] = *reinterpret_cast<const s16x8*>(&wh_slab[off]);
                bb[slot][1] = *reinterpret_cast<const s16x8*>(&wh_slab[off + 1024]);
            }
        }

        // fold chunk into running argmin (dist = wsq - 2*score)
        #pragma unroll
        for (int nt = 0; nt < 2; ++nt) {
            const int kcol = c * 256 + wk * 64 + nt * 32 + l31;
            const float wq = wsq[kcol];
            #pragma unroll
            for (int r = 0; r < 16; ++r) {
                const float dist = fmaf(-2.f, acc[nt][r], wq);
                if (dist < bestv[r]) { bestv[r] = dist; besti[r] = kcol; }
            }
        }
    }

    // ---- in-wave argmin across the 32 k-lanes ----
    #pragma unroll
    for (int off = 1; off < 32; off <<= 1) {
        #pragma unroll
        for (int r = 0; r < 16; ++r) {
            const float ov = __shfl_xor(bestv[r], off);
            const int   oi = __shfl_xor(besti[r], off);
            if (ov < bestv[r] || (ov == bestv[r] && oi < besti[r])) {
                bestv[r] = ov; besti[r] = oi;
            }
        }
    }
    if (l31 == 0) {
        #pragma unroll
        for (int r = 0; r < 16; ++r) {
            const int n = (r & 3) + 8 * (r >> 2) + 4 * lhi;   // 0..31
            wred_v[wk][n] = bestv[r];
            wred_i[wk][n] = besti[r];
        }
    }
    __syncthreads();

    // ---- final per-row reduce + loss outputs (mse from score accumulator) ----
    if (tid < 32) {
        float v  = wred_v[0][tid];
        int   i0 = wred_i[0][tid];
        #pragma unroll
        for (int wv = 1; wv < 4; ++wv) {
            const float ov = wred_v[wv][tid];
            const int   oi = wred_i[wv][tid];
            if (ov < v || (ov == v && oi < i0)) { v = ov; i0 = oi; }
        }
        kbest[tid] = i0;
        float zs = 0.f;
        #pragma unroll
        for (int r = 0; r < 32; ++r) zs += psum[r][tid];
        const float mse = (zs + v) * (1.f / 256.f);   // zsq - 2*score + wsq
        const size_t n = (size_t)bid * 32 + tid;
        out[8388608 + n] = 1.25f * mse;   // loss = (beta=0.25)*mse + mse
        out[8421376 + n] = mse;           // commitment
        out[8454144 + n] = mse;           // embedding
    }
    __syncthreads();

    // ---- quantized epilogue: gather hi+lo code rows, coalesced writes ----
    const int es = tid & 31;            // row (s-offset)
    const int dg = tid >> 5;            // 0..7 -> slab dt = dg (32 d each)
    const int kb = kbest[es];
    {
        const size_t base = (size_t)dg * 32768 + (size_t)kb * 32;
        #pragma unroll
        for (int part = 0; part < 4; ++part) {
            const s16x8 qh = *reinterpret_cast<const s16x8*>(&wh_slab[base + part * 8]);
            const s16x8 ql = *reinterpret_cast<const s16x8*>(&wl_slab[base + part * 8]);
            #pragma unroll
            for (int e = 0; e < 8; ++e) {
                const int d = dg * 32 + part * 8 + e;
                const float q = bf2f((ushort_t)qh[e]) + bf2f((ushort_t)ql[e]);
                out[(((size_t)(b * 256 + d)) << 10) + s0 + es] = q;
            }
        }
    }
}

extern "C" void kernel_launch(void* const* d_in, const int* in_sizes, int n_in,
                              void* d_out, int out_size, void* d_ws, size_t ws_size,
                              hipStream_t stream) {
    const float* z = (const float*)d_in[0];
    const float* w = (const float*)d_in[1];
    float* out = (float*)d_out;

    float*    wsq     = (float*)d_ws;                              // 4 KB
    ushort_t* wh_slab = (ushort_t*)((char*)d_ws + 4096);           // 512 KB
    ushort_t* wl_slab = (ushort_t*)((char*)d_ws + 4096 + 524288);  // 512 KB

    vq_wprep<<<16,   256, 0, stream>>>(w, wh_slab, wl_slab, wsq);
    vq_mfma <<<1024, 256, 0, stream>>>(z, wh_slab, wl_slab, wsq, out);
}

// Round 8
// 77.405 us; speedup vs baseline: 5.3158x; 5.3158x over previous
//
#include <hip/hip_runtime.h>

// VQ-VAE quantizer forward. 1-term bf16 MFMA (zh*wh); W staged into LDS via
// global_load_lds double-buffer with counted vmcnt (never drained in-loop);
// A fragments register-resident; mse from the score accumulator.
// z: [32, 256, 32, 32] fp32; weight: [256, 1024] fp32.
// out: quantized [8388608] ++ loss [32768] ++ commitment [32768] ++ embedding [32768]

typedef unsigned short ushort_t;
typedef short          s16x4  __attribute__((ext_vector_type(4)));
typedef short          s16x8  __attribute__((ext_vector_type(8)));
typedef float          f32x16 __attribute__((ext_vector_type(16)));

#define STAGE_BYTES 18432          // 256 k * 36 ushort * 2B
#define ROW_U       36             // 32 data + 4 pad ushorts per k-row

__device__ __forceinline__ ushort_t f2bf(float x) {
    unsigned int u = __float_as_uint(x);
    u += 0x7fffu + ((u >> 16) & 1u);          // RNE
    return (ushort_t)(u >> 16);
}
__device__ __forceinline__ float bf2f(ushort_t h) {
    return __uint_as_float(((unsigned int)h) << 16);
}

// async global->LDS (width literal). LDS addr passed as 32-bit offset-int.
__device__ __forceinline__ void dma16(const void* g, const void* l) {
    __builtin_amdgcn_global_load_lds(
        (const __attribute__((address_space(1))) unsigned int*)(unsigned long long)(uintptr_t)g,
        (__attribute__((address_space(3))) unsigned int*)(unsigned int)(uintptr_t)l,
        16, 0, 0);
}
__device__ __forceinline__ void dma4(const void* g, const void* l) {
    __builtin_amdgcn_global_load_lds(
        (const __attribute__((address_space(1))) unsigned int*)(unsigned long long)(uintptr_t)g,
        (__attribute__((address_space(3))) unsigned int*)(unsigned int)(uintptr_t)l,
        4, 0, 0);
}

// ---- prep: wsq + stage-major padded hi slab + plain lo slab ----
// hi (ushort idx): ((k>>8)*8 + (d>>5))*9216 + (k&255)*36 + (d&31)
// lo (ushort idx): k*256 + d
__global__ __launch_bounds__(256)
void vq_wprep(const float* __restrict__ w,
              ushort_t* __restrict__ hi, ushort_t* __restrict__ lo,
              float* __restrict__ wsq) {
    __shared__ float tile[64][65];
    __shared__ float psum[64][4];
    const int t  = threadIdx.x;
    const int kt = blockIdx.x;          // 16 blocks, 64 codes each
    const int kk = t >> 2;              // k-local 0..63
    const int dq = t & 3;               // d-quarter within 32-d group
    const int k  = kt * 64 + kk;
    float acc = 0.f;
    for (int dt6 = 0; dt6 < 4; ++dt6) {
        __syncthreads();
        #pragma unroll
        for (int i = 0; i < 16; ++i) {
            const int lin = t + 256 * i;
            const int dd = lin >> 6, k2 = lin & 63;
            tile[dd][k2] = w[(size_t)(dt6 * 64 + dd) * 1024 + kt * 64 + k2];
        }
        __syncthreads();
        #pragma unroll
        for (int half = 0; half < 2; ++half) {
            const int st = dt6 * 2 + half;          // stage d-index (d>>5)
            s16x8 hv, lv;
            #pragma unroll
            for (int e = 0; e < 8; ++e) {
                const int dd = half * 32 + dq * 8 + e;
                const float v = tile[dd][kk];
                const ushort_t hb = f2bf(v);
                hv[e] = (short)hb;
                lv[e] = (short)f2bf(v - bf2f(hb));
                acc = fmaf(v, v, acc);
            }
            const size_t hbase = (size_t)((k >> 8) * 8 + st) * 9216
                               + (size_t)(k & 255) * ROW_U + dq * 8;
            #pragma unroll
            for (int e = 0; e < 8; ++e) hi[hbase + e] = (ushort_t)hv[e];
            const size_t lbase = (size_t)k * 256 + st * 32 + dq * 8;
            *reinterpret_cast<s16x8*>(&lo[lbase]) = lv;
        }
    }
    psum[kk][dq] = acc;
    __syncthreads();
    if (t < 64)
        wsq[kt * 64 + t] = psum[t][0] + psum[t][1] + psum[t][2] + psum[t][3];
}

// ---- main: M=64 rows/block, 512 blocks, 2 blocks/CU ----
__global__ __launch_bounds__(256, 2)
void vq_mfma(const float* __restrict__ z,
             const ushort_t* __restrict__ wh_slab, const ushort_t* __restrict__ wl_slab,
             const float* __restrict__ wsq, float* __restrict__ out) {
    __shared__ __align__(16) char smem[73728];   // 4 x 18KB bufs; z_hi overlaid on tail
    __shared__ float psum[16][64];
    __shared__ float wred_v[4][64];
    __shared__ int   wred_i[4][64];
    __shared__ int   kbest[64];

    ushort_t (*z_hi)[268] = (ushort_t (*)[268])(smem + 39424);  // 64*268*2 = 34304 -> ends at 73728

    const int tid  = threadIdx.x;
    const int bid  = blockIdx.x;
    const int b    = bid >> 4;
    const int s0   = (bid & 15) * 64;
    const int lane = tid & 63;
    const int wid  = tid >> 6;
    const int wk   = wid;               // wave -> k-quarter of each 256-chunk
    const int l31  = lane & 31;
    const int lhi  = lane >> 5;
    const char* wh_c = (const char*)wh_slab;

    // ---- stage z -> z_hi [n][d] + z^2 partials (z read ONCE) ----
    {
        const int u  = tid & 15;
        const int sc = u * 4;
        const int dr = tid >> 4;        // 0..15
        float p[4] = {0.f, 0.f, 0.f, 0.f};
        for (int it = 0; it < 16; ++it) {
            const int d = it * 16 + dr;
            const float4 v = *reinterpret_cast<const float4*>(
                &z[(((size_t)(b * 256 + d)) << 10) + s0 + sc]);
            const float vv[4] = {v.x, v.y, v.z, v.w};
            #pragma unroll
            for (int jj = 0; jj < 4; ++jj) {
                const int j = (jj + u) & 3;           // stagger write banks
                z_hi[sc + j][d] = f2bf(vv[j]);
                p[j] = fmaf(vv[j], vv[j], p[j]);
            }
        }
        #pragma unroll
        for (int j = 0; j < 4; ++j) psum[dr][sc + j] = p[j];
    }
    asm volatile("s_waitcnt lgkmcnt(0)" ::: "memory");
    __builtin_amdgcn_s_barrier();

    // ---- issue DMA for stages 0,1 (bufs 0,1: bytes 0..36864, disjoint from z_hi) ----
    #pragma unroll
    for (int st = 0; st < 2; ++st) {
        const char* src = wh_c + (size_t)st * STAGE_BYTES;
        const unsigned dst = st * STAGE_BYTES;
        #pragma unroll
        for (int i = 0; i < 4; ++i)
            dma16(src + i * 4096 + tid * 16, smem + dst + i * 4096 + wid * 1024);
        #pragma unroll
        for (int jj = 0; jj < 2; ++jj)
            dma4(src + 16384 + jj * 1024 + tid * 4, smem + dst + 16384 + jj * 1024 + wid * 256);
    }

    // ---- A fragments -> registers (row = m*32+l31, d = j*16 + lhi*8 + e) ----
    s16x8 a[2][16];
    #pragma unroll
    for (int m = 0; m < 2; ++m)
        #pragma unroll
        for (int j = 0; j < 16; ++j)
            a[m][j] = *reinterpret_cast<const s16x8*>(&z_hi[m * 32 + l31][j * 16 + lhi * 8]);

    asm volatile("s_waitcnt lgkmcnt(0)" ::: "memory");
    __builtin_amdgcn_s_barrier();      // all A-loads done -> z_hi region reusable as bufs 2,3

    float bestv[2][16];
    int   besti[2][16];
    #pragma unroll
    for (int m = 0; m < 2; ++m)
        #pragma unroll
        for (int r = 0; r < 16; ++r) { bestv[m][r] = 1e30f; besti[m][r] = 0; }

    f32x16 acc[2][2];
    const int brow0 = (wk * 64 + l31) * (ROW_U * 2) + lhi * 16;   // byte offset of lane's nt=0 row

    for (int c = 0; c < 4; ++c) {           // k-chunks of 256 (rolled)
        #pragma unroll
        for (int dt = 0; dt < 8; ++dt) {    // 32-d stages; buf = dt&3 (compile-time)
            asm volatile("s_waitcnt vmcnt(6)" ::: "memory");   // stage s landed; s+1 in flight
            __builtin_amdgcn_s_barrier();

            // issue DMA for stage s+2 into buf (dt+2)&3 (src wraps harmlessly at tail)
            {
                const int sn = (c * 8 + dt + 2) & 31;
                const char* src = wh_c + (size_t)sn * STAGE_BYTES;
                const unsigned dst = ((dt + 2) & 3) * STAGE_BYTES;
                #pragma unroll
                for (int i = 0; i < 4; ++i)
                    dma16(src + i * 4096 + tid * 16, smem + dst + i * 4096 + wid * 1024);
                #pragma unroll
                for (int jj = 0; jj < 2; ++jj)
                    dma4(src + 16384 + jj * 1024 + tid * 4,
                         smem + dst + 16384 + jj * 1024 + wid * 256);
            }

            if (dt == 0) {
                #pragma unroll
                for (int m = 0; m < 2; ++m)
                    #pragma unroll
                    for (int nt = 0; nt < 2; ++nt)
                        #pragma unroll
                        for (int e = 0; e < 16; ++e) acc[m][nt][e] = 0.f;
            }

            const char* bufp = smem + (dt & 3) * STAGE_BYTES;
            __builtin_amdgcn_s_setprio(1);
            #pragma unroll
            for (int ds = 0; ds < 2; ++ds) {
                const int j = dt * 2 + ds;
                #pragma unroll
                for (int nt = 0; nt < 2; ++nt) {
                    const char* bp = bufp + brow0 + nt * (32 * ROW_U * 2) + ds * 32;
                    const s16x4 b0 = *reinterpret_cast<const s16x4*>(bp);
                    const s16x4 b1 = *reinterpret_cast<const s16x4*>(bp + 8);
                    s16x8 bf;
                    bf[0] = b0[0]; bf[1] = b0[1]; bf[2] = b0[2]; bf[3] = b0[3];
                    bf[4] = b1[0]; bf[5] = b1[1]; bf[6] = b1[2]; bf[7] = b1[3];
                    acc[0][nt] = __builtin_amdgcn_mfma_f32_32x32x16_bf16(
                        a[0][j], bf, acc[0][nt], 0, 0, 0);
                    acc[1][nt] = __builtin_amdgcn_mfma_f32_32x32x16_bf16(
                        a[1][j], bf, acc[1][nt], 0, 0, 0);
                }
            }
            __builtin_amdgcn_s_setprio(0);

            if (dt == 7) {   // fold chunk into running argmin (dist = wsq - 2*score)
                #pragma unroll
                for (int nt = 0; nt < 2; ++nt) {
                    const int kcol = c * 256 + wk * 64 + nt * 32 + l31;
                    const float wq = wsq[kcol];
                    #pragma unroll
                    for (int m = 0; m < 2; ++m)
                        #pragma unroll
                        for (int r = 0; r < 16; ++r) {
                            const float dist = fmaf(-2.f, acc[m][nt][r], wq);
                            if (dist < bestv[m][r]) { bestv[m][r] = dist; besti[m][r] = kcol; }
                        }
                }
            }
        }
    }

    // ---- in-wave argmin across the 32 k-lanes ----
    #pragma unroll
    for (int off = 1; off < 32; off <<= 1) {
        #pragma unroll
        for (int m = 0; m < 2; ++m)
            #pragma unroll
            for (int r = 0; r < 16; ++r) {
                const float ov = __shfl_xor(bestv[m][r], off);
                const int   oi = __shfl_xor(besti[m][r], off);
                if (ov < bestv[m][r] || (ov == bestv[m][r] && oi < besti[m][r])) {
                    bestv[m][r] = ov; besti[m][r] = oi;
                }
            }
    }
    if (l31 == 0) {
        #pragma unroll
        for (int m = 0; m < 2; ++m)
            #pragma unroll
            for (int r = 0; r < 16; ++r) {
                const int n = m * 32 + (r & 3) + 8 * (r >> 2) + 4 * lhi;
                wred_v[wk][n] = bestv[m][r];
                wred_i[wk][n] = besti[m][r];
            }
    }
    __syncthreads();   // full drain (also retires the harmless tail DMAs)

    // ---- final per-row reduce + loss outputs (mse from score accumulator) ----
    if (tid < 64) {
        float v  = wred_v[0][tid];
        int   i0 = wred_i[0][tid];
        #pragma unroll
        for (int wv = 1; wv < 4; ++wv) {
            const float ov = wred_v[wv][tid];
            const int   oi = wred_i[wv][tid];
            if (ov < v || (ov == v && oi < i0)) { v = ov; i0 = oi; }
        }
        kbest[tid] = i0;
        float zs = 0.f;
        #pragma unroll
        for (int r = 0; r < 16; ++r) zs += psum[r][tid];
        const float mse = (zs + v) * (1.f / 256.f);   // zsq - 2*score + wsq
        const size_t n = (size_t)bid * 64 + tid;
        out[8388608 + n] = 1.25f * mse;   // loss = (beta=0.25)*mse + mse
        out[8421376 + n] = mse;           // commitment
        out[8454144 + n] = mse;           // embedding
    }
    __syncthreads();

    // ---- quantized epilogue: gather hi (stage-major) + lo (plain), coalesced writes ----
    const int es = tid & 63;
    const int dg = tid >> 6;            // 0..3 -> d-range dg*64..+63
    const int kb = kbest[es];
    #pragma unroll
    for (int si = 0; si < 2; ++si) {
        const int dt = dg * 2 + si;     // stage d-index
        const size_t hbase = (size_t)((kb >> 8) * 8 + dt) * 9216 + (size_t)(kb & 255) * ROW_U;
        const size_t lbase = (size_t)kb * 256 + dt * 32;
        #pragma unroll
        for (int part = 0; part < 4; ++part) {
            const s16x4 qh0 = *reinterpret_cast<const s16x4*>(&wh_slab[hbase + part * 8]);
            const s16x4 qh1 = *reinterpret_cast<const s16x4*>(&wh_slab[hbase + part * 8 + 4]);
            const s16x8 ql  = *reinterpret_cast<const s16x8*>(&wl_slab[lbase + part * 8]);
            #pragma unroll
            for (int e = 0; e < 8; ++e) {
                const int d = dt * 32 + part * 8 + e;
                const short h = (e < 4) ? qh0[e] : qh1[e - 4];
                const float q = bf2f((ushort_t)h) + bf2f((ushort_t)ql[e]);
                out[(((size_t)(b * 256 + d)) << 10) + s0 + es] = q;
            }
        }
    }
}

extern "C" void kernel_launch(void* const* d_in, const int* in_sizes, int n_in,
                              void* d_out, int out_size, void* d_ws, size_t ws_size,
                              hipStream_t stream) {
    const float* z = (const float*)d_in[0];
    const float* w = (const float*)d_in[1];
    float* out = (float*)d_out;

    float*    wsq     = (float*)d_ws;                               // 4 KB
    ushort_t* wh_slab = (ushort_t*)((char*)d_ws + 4096);            // 576 KB stage-major padded
    ushort_t* wl_slab = (ushort_t*)((char*)d_ws + 4096 + 589824);   // 512 KB plain

    vq_wprep<<<16,  256, 0, stream>>>(w, wh_slab, wl_slab, wsq);
    vq_mfma <<<512, 256, 0, stream>>>(z, wh_slab, wl_slab, wsq, out);
}